// Round 1
// baseline (1114.804 us; speedup 1.0000x reference)
//
#include <hip/hip_runtime.h>
#include <hip/hip_bf16.h>

#define N_NODES 100000
#define N_EDGES 1600000
#define N_PAIRS 500000
#define MPAD    100032   // 1563*64, 64-row padded node count
#define NF      128

typedef __bf16 bf16x8 __attribute__((ext_vector_type(8)));
typedef float  f32x4  __attribute__((ext_vector_type(4)));
typedef unsigned int   u32;
typedef unsigned short u16;

__device__ inline u16   f2b(float f) { __bf16 b = (__bf16)f; return __builtin_bit_cast(u16, b); }
__device__ inline float b2f(u16 u)   { return (float)__builtin_bit_cast(__bf16, u); }

// ---------- conversion kernels ----------
// dst is [N][K] bf16 (transposed), src is [K][N] f32
__global__ void k_convT(const float* __restrict__ src, u16* __restrict__ dst, int K, int N) {
    int i = blockIdx.x * 256 + threadIdx.x;
    if (i >= K * N) return;
    int n = i / K, k = i - n * K;
    dst[i] = f2b(src[k * N + n]);
}

// x f32 [N_NODES][128] -> packed bf16x2 [MPAD][64], pad rows zeroed
__global__ void k_convX(const float2* __restrict__ x, u32* __restrict__ xb) {
    int i = blockIdx.x * 256 + threadIdx.x;
    if (i >= MPAD * 64) return;
    int node = i >> 6;
    float2 v = make_float2(0.f, 0.f);
    if (node < N_NODES) v = x[i];
    xb[i] = (u32)f2b(v.x) | ((u32)f2b(v.y) << 16);
}

// ---------- CSR build ----------
__global__ void k_hist(const int* __restrict__ row, int* __restrict__ deg) {
    int e = blockIdx.x * 256 + threadIdx.x;
    if (e >= N_EDGES) return;
    atomicAdd(&deg[row[e]], 1);
}

__global__ void k_scan1(const int* __restrict__ deg, int* __restrict__ incl, int* __restrict__ bsums) {
    __shared__ int s[1024];
    int t = threadIdx.x;
    int g = blockIdx.x * 1024 + t;
    s[t] = (g < N_NODES) ? deg[g] : 0;
    __syncthreads();
    for (int d = 1; d < 1024; d <<= 1) {
        int add = (t >= d) ? s[t - d] : 0;
        __syncthreads();
        s[t] += add;
        __syncthreads();
    }
    if (g < N_NODES) incl[g] = s[t];
    if (t == 1023) bsums[blockIdx.x] = s[1023];
}

__global__ void k_scan2(int* __restrict__ bsums, int nb) {
    __shared__ int s[128];
    int t = threadIdx.x;
    s[t] = (t < nb) ? bsums[t] : 0;
    __syncthreads();
    for (int d = 1; d < 128; d <<= 1) {
        int add = (t >= d) ? s[t - d] : 0;
        __syncthreads();
        s[t] += add;
        __syncthreads();
    }
    if (t < nb) bsums[t] = (t == 0) ? 0 : s[t - 1];
}

__global__ void k_scan3(const int* __restrict__ incl, const int* __restrict__ bsums,
                        int* __restrict__ rowptr, int* __restrict__ cursor) {
    int g = blockIdx.x * 256 + threadIdx.x;
    if (g == 0) { rowptr[0] = 0; cursor[0] = 0; }
    if (g >= N_NODES) return;
    int v = incl[g] + bsums[g >> 10];
    rowptr[g + 1] = v;
    if (g + 1 < N_NODES) cursor[g + 1] = v;
}

__global__ void k_scatter(const int* __restrict__ row, const int* __restrict__ col,
                          const float* __restrict__ w, int* __restrict__ cursor,
                          int* __restrict__ ccol, float* __restrict__ cw) {
    int e = blockIdx.x * 256 + threadIdx.x;
    if (e >= N_EDGES) return;
    int pos = atomicAdd(&cursor[row[e]], 1);
    ccol[pos] = col[e];
    cw[pos]   = w[e];
}

// ---------- fused dual GEMM: HS = A@Ws (f32), SUP = A@Wn (bf16) ----------
// A: [MPAD][128] bf16 row-major; WsT/WnT: [128][128] bf16 (N-major, i.e. W^T)
__global__ void k_gemm_pair(const u16* __restrict__ A, const u16* __restrict__ WsT,
                            const u16* __restrict__ WnT, float* __restrict__ HS,
                            u16* __restrict__ SUP) {
    int wid = threadIdx.x >> 6, lane = threadIdx.x & 63;
    int lr = lane & 15, lg = lane >> 4;
    int m0 = blockIdx.x * 64;
    const u16* WT = (wid < 2) ? WsT : WnT;
    int n0 = (wid & 1) * 64;
    f32x4 acc[4][4] = {};
    for (int ks = 0; ks < 4; ++ks) {
        int k0 = ks * 32 + lg * 8;
        bf16x8 a[4], b[4];
        #pragma unroll
        for (int r = 0; r < 4; ++r)
            a[r] = *reinterpret_cast<const bf16x8*>(A + (size_t)(m0 + r * 16 + lr) * NF + k0);
        #pragma unroll
        for (int c = 0; c < 4; ++c)
            b[c] = *reinterpret_cast<const bf16x8*>(WT + (size_t)(n0 + c * 16 + lr) * NF + k0);
        #pragma unroll
        for (int r = 0; r < 4; ++r)
            #pragma unroll
            for (int c = 0; c < 4; ++c)
                acc[r][c] = __builtin_amdgcn_mfma_f32_16x16x32_bf16(a[r], b[c], acc[r][c], 0, 0, 0);
    }
    #pragma unroll
    for (int r = 0; r < 4; ++r) {
        #pragma unroll
        for (int reg = 0; reg < 4; ++reg) {
            int m = m0 + r * 16 + lg * 4 + reg;
            if (m >= N_NODES) continue;
            #pragma unroll
            for (int c = 0; c < 4; ++c) {
                int col = n0 + c * 16 + lr;
                float v = acc[r][c][reg];
                if (wid < 2) HS[(size_t)m * NF + col] = v;
                else         SUP[(size_t)m * NF + col] = f2b(v);
            }
        }
    }
}

// ---------- aggregation: out = (relu?)(HS + sum_e w_e * SUP[col_e] + bias) ----------
// one wave per node, lane handles features 2*lane, 2*lane+1
__global__ void k_aggregate(const u32* __restrict__ SUP2, const float2* __restrict__ HS2,
                            const int* __restrict__ rowptr, const int* __restrict__ ccol,
                            const float* __restrict__ cw, const float* __restrict__ bias,
                            u32* __restrict__ Hout, float2* __restrict__ Zout, int relu) {
    int node = blockIdx.x * 4 + (threadIdx.x >> 6);
    int lane = threadIdx.x & 63;
    if (node >= N_NODES) return;
    float a0 = 0.f, a1 = 0.f;
    int e0 = rowptr[node], e1 = rowptr[node + 1];
    for (int e = e0; e < e1; ++e) {
        int c = ccol[e];
        float w = cw[e];
        u32 v = SUP2[(size_t)c * 64 + lane];
        a0 = fmaf(w, b2f((u16)(v & 0xffff)), a0);
        a1 = fmaf(w, b2f((u16)(v >> 16)), a1);
    }
    float2 hsv = HS2[(size_t)node * 64 + lane];
    float o0 = hsv.x + a0 + bias[2 * lane];
    float o1 = hsv.y + a1 + bias[2 * lane + 1];
    if (relu) { o0 = fmaxf(o0, 0.f); o1 = fmaxf(o1, 0.f); }
    Hout[(size_t)node * 64 + lane] = (u32)f2b(o0) | ((u32)f2b(o1) << 16);
    if (Zout) Zout[(size_t)node * 64 + lane] = make_float2(o0, o1);
}

// ---------- decoder: p = sigmoid(relu([z[xi]||z[yi]]@W1 + b1)@w2 + b2) ----------
// block = 4 waves, each wave does 32 pairs (2 row-tiles); W1T: [128][256] bf16
__global__ void k_decoder(const u16* __restrict__ ZB, const int* __restrict__ xidx,
                          const int* __restrict__ yidx, const u16* __restrict__ W1T,
                          const float* __restrict__ b1, const float* __restrict__ w2,
                          const float* __restrict__ b2, float* __restrict__ outp) {
    int wid = threadIdx.x >> 6, lane = threadIdx.x & 63;
    int lr = lane & 15, lg = lane >> 4;
    int p0 = blockIdx.x * 128 + wid * 32;
    int px[2], py[2];
    #pragma unroll
    for (int rt = 0; rt < 2; ++rt) {
        int p = p0 + rt * 16 + lr;
        int pc = (p < N_PAIRS) ? p : 0;
        px[rt] = xidx[pc];
        py[rt] = yidx[pc];
    }
    f32x4 acc[2][8] = {};
    for (int ks = 0; ks < 8; ++ks) {
        int kk = ks * 32 + lg * 8;
        bf16x8 a[2], b[8];
        #pragma unroll
        for (int rt = 0; rt < 2; ++rt) {
            size_t base = (kk < 128) ? ((size_t)px[rt] * NF + kk)
                                     : ((size_t)py[rt] * NF + (kk - 128));
            a[rt] = *reinterpret_cast<const bf16x8*>(ZB + base);
        }
        #pragma unroll
        for (int c = 0; c < 8; ++c)
            b[c] = *reinterpret_cast<const bf16x8*>(W1T + (size_t)(c * 16 + lr) * 256 + kk);
        #pragma unroll
        for (int rt = 0; rt < 2; ++rt)
            #pragma unroll
            for (int c = 0; c < 8; ++c)
                acc[rt][c] = __builtin_amdgcn_mfma_f32_16x16x32_bf16(a[rt], b[c], acc[rt][c], 0, 0, 0);
    }
    float vb1[8], vw2[8];
    #pragma unroll
    for (int c = 0; c < 8; ++c) { int col = c * 16 + lr; vb1[c] = b1[col]; vw2[c] = w2[col]; }
    float vb2 = b2[0];
    #pragma unroll
    for (int rt = 0; rt < 2; ++rt) {
        #pragma unroll
        for (int reg = 0; reg < 4; ++reg) {
            float part = 0.f;
            #pragma unroll
            for (int c = 0; c < 8; ++c) {
                float h = fmaxf(acc[rt][c][reg] + vb1[c], 0.f);
                part = fmaf(h, vw2[c], part);
            }
            #pragma unroll
            for (int m = 1; m < 16; m <<= 1) part += __shfl_xor(part, m, 64);
            int p = p0 + rt * 16 + lg * 4 + reg;
            if (lr == 0 && p < N_PAIRS) outp[p] = 1.f / (1.f + __expf(-(part + vb2)));
        }
    }
}

extern "C" void kernel_launch(void* const* d_in, const int* in_sizes, int n_in,
                              void* d_out, int out_size, void* d_ws, size_t ws_size,
                              hipStream_t stream) {
    const float* x      = (const float*)d_in[0];
    const int* edge_row = (const int*)d_in[1];
    const int* edge_col = (const int*)d_in[2];
    const float* edge_w = (const float*)d_in[3];
    const int* x_idx    = (const int*)d_in[4];
    const int* y_idx    = (const int*)d_in[5];
    const float* gws[3] = {(const float*)d_in[6], (const float*)d_in[9],  (const float*)d_in[12]};
    const float* gwn[3] = {(const float*)d_in[7], (const float*)d_in[10], (const float*)d_in[13]};
    const float* gb[3]  = {(const float*)d_in[8], (const float*)d_in[11], (const float*)d_in[14]};
    const float* dw1 = (const float*)d_in[15];
    const float* db1 = (const float*)d_in[16];
    const float* dw2 = (const float*)d_in[17];
    const float* db2 = (const float*)d_in[18];
    float* out_p = (float*)d_out;        // [N_PAIRS]
    float* out_z = out_p + N_PAIRS;      // [N_NODES*128]

    char* base = (char*)d_ws;
    size_t off = 0;
    auto alloc = [&](size_t bytes) -> void* {
        void* p = base + off;
        off = (off + bytes + 255) & ~(size_t)255;
        return p;
    };
    u16* h0  = (u16*)alloc((size_t)MPAD * NF * 2);
    u16* h1  = (u16*)alloc((size_t)MPAD * NF * 2);
    u16* sup = (u16*)alloc((size_t)MPAD * NF * 2);
    float* hs = (float*)alloc((size_t)MPAD * NF * 4);
    u16* wT[6];
    for (int i = 0; i < 6; ++i) wT[i] = (u16*)alloc(128 * 128 * 2);
    u16* w1T  = (u16*)alloc(256 * 128 * 2);
    int* deg    = (int*)alloc(N_NODES * 4);
    int* incl   = (int*)alloc(N_NODES * 4);
    int* bsums  = (int*)alloc(128 * 4);
    int* rowptr = (int*)alloc((N_NODES + 1) * 4);
    int* cursor = (int*)alloc(N_NODES * 4);
    int* ccol   = (int*)alloc(N_EDGES * 4);
    float* cwt  = (float*)alloc(N_EDGES * 4);

    hipMemsetAsync(deg, 0, N_NODES * 4, stream);

    // weight conversion (transposed to [N][K] bf16)
    for (int l = 0; l < 3; ++l) {
        k_convT<<<64, 256, 0, stream>>>(gws[l], wT[2 * l],     128, 128);
        k_convT<<<64, 256, 0, stream>>>(gwn[l], wT[2 * l + 1], 128, 128);
    }
    k_convT<<<128, 256, 0, stream>>>(dw1, w1T, 256, 128);
    k_convX<<<(MPAD * 64 + 255) / 256, 256, 0, stream>>>((const float2*)x, (u32*)h0);

    // CSR build
    k_hist<<<(N_EDGES + 255) / 256, 256, 0, stream>>>(edge_row, deg);
    k_scan1<<<98, 1024, 0, stream>>>(deg, incl, bsums);
    k_scan2<<<1, 128, 0, stream>>>(bsums, 98);
    k_scan3<<<(N_NODES + 255) / 256, 256, 0, stream>>>(incl, bsums, rowptr, cursor);
    k_scatter<<<(N_EDGES + 255) / 256, 256, 0, stream>>>(edge_row, edge_col, edge_w, cursor, ccol, cwt);

    const int GB = MPAD / 64;    // 1563
    const int AB = N_NODES / 4;  // 25000

    // layer 1: x -> h1
    k_gemm_pair<<<GB, 256, 0, stream>>>(h0, wT[0], wT[1], hs, sup);
    k_aggregate<<<AB, 256, 0, stream>>>((const u32*)sup, (const float2*)hs, rowptr, ccol, cwt,
                                        gb[0], (u32*)h1, nullptr, 1);
    // layer 2: h1 -> h0
    k_gemm_pair<<<GB, 256, 0, stream>>>(h1, wT[2], wT[3], hs, sup);
    k_aggregate<<<AB, 256, 0, stream>>>((const u32*)sup, (const float2*)hs, rowptr, ccol, cwt,
                                        gb[1], (u32*)h0, nullptr, 1);
    // layer 3: h0 -> h1 (=z bf16) + z f32 to d_out
    k_gemm_pair<<<GB, 256, 0, stream>>>(h0, wT[4], wT[5], hs, sup);
    k_aggregate<<<AB, 256, 0, stream>>>((const u32*)sup, (const float2*)hs, rowptr, ccol, cwt,
                                        gb[2], (u32*)h1, (float2*)out_z, 0);
    // decoder
    k_decoder<<<(N_PAIRS + 127) / 128, 256, 0, stream>>>(h1, x_idx, y_idx, w1T, db1, dw2, db2, out_p);
}

// Round 2
// 905.042 us; speedup vs baseline: 1.2318x; 1.2318x over previous
//
#include <hip/hip_runtime.h>
#include <hip/hip_bf16.h>

#define N_NODES 100000
#define N_EDGES 1600000
#define N_PAIRS 500000
#define MPAD    100032   // 1563*64, 64-row padded node count
#define NF      128

typedef __bf16 bf16x8 __attribute__((ext_vector_type(8)));
typedef float  f32x4  __attribute__((ext_vector_type(4)));
typedef unsigned int   u32;
typedef unsigned short u16;

__device__ inline u16   f2b(float f) { __bf16 b = (__bf16)f; return __builtin_bit_cast(u16, b); }
__device__ inline float b2f(u16 u)   { return (float)__builtin_bit_cast(__bf16, u); }

// ---------- conversion kernels ----------
// dst is [N][K] bf16 (transposed), src is [K][N] f32
__global__ void k_convT(const float* __restrict__ src, u16* __restrict__ dst, int K, int N) {
    int i = blockIdx.x * 256 + threadIdx.x;
    if (i >= K * N) return;
    int n = i / K, k = i - n * K;
    dst[i] = f2b(src[k * N + n]);
}

// x f32 [N_NODES][128] -> packed bf16x2 [MPAD][64], pad rows zeroed
__global__ void k_convX(const float2* __restrict__ x, u32* __restrict__ xb) {
    int i = blockIdx.x * 256 + threadIdx.x;
    if (i >= MPAD * 64) return;
    int node = i >> 6;
    float2 v = make_float2(0.f, 0.f);
    if (node < N_NODES) v = x[i];
    xb[i] = (u32)f2b(v.x) | ((u32)f2b(v.y) << 16);
}

// ---------- CSR build ----------
__global__ void k_hist(const int* __restrict__ row, int* __restrict__ deg) {
    int e = blockIdx.x * 256 + threadIdx.x;
    if (e >= N_EDGES) return;
    atomicAdd(&deg[row[e]], 1);
}

__global__ void k_scan1(const int* __restrict__ deg, int* __restrict__ incl, int* __restrict__ bsums) {
    __shared__ int s[1024];
    int t = threadIdx.x;
    int g = blockIdx.x * 1024 + t;
    s[t] = (g < N_NODES) ? deg[g] : 0;
    __syncthreads();
    for (int d = 1; d < 1024; d <<= 1) {
        int add = (t >= d) ? s[t - d] : 0;
        __syncthreads();
        s[t] += add;
        __syncthreads();
    }
    if (g < N_NODES) incl[g] = s[t];
    if (t == 1023) bsums[blockIdx.x] = s[1023];
}

__global__ void k_scan2(int* __restrict__ bsums, int nb) {
    __shared__ int s[128];
    int t = threadIdx.x;
    s[t] = (t < nb) ? bsums[t] : 0;
    __syncthreads();
    for (int d = 1; d < 128; d <<= 1) {
        int add = (t >= d) ? s[t - d] : 0;
        __syncthreads();
        s[t] += add;
        __syncthreads();
    }
    if (t < nb) bsums[t] = (t == 0) ? 0 : s[t - 1];
}

__global__ void k_scan3(const int* __restrict__ incl, const int* __restrict__ bsums,
                        int* __restrict__ rowptr, int* __restrict__ cursor) {
    int g = blockIdx.x * 256 + threadIdx.x;
    if (g == 0) { rowptr[0] = 0; cursor[0] = 0; }
    if (g >= N_NODES) return;
    int v = incl[g] + bsums[g >> 10];
    rowptr[g + 1] = v;
    if (g + 1 < N_NODES) cursor[g + 1] = v;
}

__global__ void k_scatter(const int* __restrict__ row, const int* __restrict__ col,
                          const float* __restrict__ w, int* __restrict__ cursor,
                          int* __restrict__ ccol, float* __restrict__ cw) {
    int e = blockIdx.x * 256 + threadIdx.x;
    if (e >= N_EDGES) return;
    int pos = atomicAdd(&cursor[row[e]], 1);
    ccol[pos] = col[e];
    cw[pos]   = w[e];
}

// ---------- fused dual GEMM: HS = A@Ws (f32), SUPc = A@Wn (bf16, chunk-major) ----------
// A: [MPAD][128] bf16 row-major; WsT/WnT: [128][128] bf16 (N-major, i.e. W^T)
// SUPc layout: [8 chunks][MPAD][16 feats] u16 -> per-edge gather is 32B from a 3.2MB chunk
__global__ void k_gemm_pair(const u16* __restrict__ A, const u16* __restrict__ WsT,
                            const u16* __restrict__ WnT, float* __restrict__ HS,
                            u16* __restrict__ SUPc) {
    int wid = threadIdx.x >> 6, lane = threadIdx.x & 63;
    int lr = lane & 15, lg = lane >> 4;
    int m0 = blockIdx.x * 64;
    const u16* WT = (wid < 2) ? WsT : WnT;
    int n0 = (wid & 1) * 64;
    f32x4 acc[4][4] = {};
    for (int ks = 0; ks < 4; ++ks) {
        int k0 = ks * 32 + lg * 8;
        bf16x8 a[4], b[4];
        #pragma unroll
        for (int r = 0; r < 4; ++r)
            a[r] = *reinterpret_cast<const bf16x8*>(A + (size_t)(m0 + r * 16 + lr) * NF + k0);
        #pragma unroll
        for (int c = 0; c < 4; ++c)
            b[c] = *reinterpret_cast<const bf16x8*>(WT + (size_t)(n0 + c * 16 + lr) * NF + k0);
        #pragma unroll
        for (int r = 0; r < 4; ++r)
            #pragma unroll
            for (int c = 0; c < 4; ++c)
                acc[r][c] = __builtin_amdgcn_mfma_f32_16x16x32_bf16(a[r], b[c], acc[r][c], 0, 0, 0);
    }
    #pragma unroll
    for (int r = 0; r < 4; ++r) {
        #pragma unroll
        for (int reg = 0; reg < 4; ++reg) {
            int m = m0 + r * 16 + lg * 4 + reg;
            if (m >= N_NODES) continue;
            #pragma unroll
            for (int c = 0; c < 4; ++c) {
                int col = n0 + c * 16 + lr;
                float v = acc[r][c][reg];
                if (wid < 2) HS[(size_t)m * NF + col] = v;
                else {
                    int ch = col >> 4, cc = col & 15;
                    SUPc[((size_t)ch * MPAD + m) * 16 + cc] = f2b(v);
                }
            }
        }
    }
}

// ---------- dual GEMM for decoder precompute: U = Z@W1a + b1, V = Z@W1b (both bf16, row-major) ----------
__global__ void k_gemm_uv(const u16* __restrict__ A, const u16* __restrict__ W1aT,
                          const u16* __restrict__ W1bT, const float* __restrict__ b1,
                          u16* __restrict__ U, u16* __restrict__ V) {
    int wid = threadIdx.x >> 6, lane = threadIdx.x & 63;
    int lr = lane & 15, lg = lane >> 4;
    int m0 = blockIdx.x * 64;
    const u16* WT = (wid < 2) ? W1aT : W1bT;
    u16* OUT = (wid < 2) ? U : V;
    int addb = (wid < 2) ? 1 : 0;
    int n0 = (wid & 1) * 64;
    f32x4 acc[4][4] = {};
    for (int ks = 0; ks < 4; ++ks) {
        int k0 = ks * 32 + lg * 8;
        bf16x8 a[4], b[4];
        #pragma unroll
        for (int r = 0; r < 4; ++r)
            a[r] = *reinterpret_cast<const bf16x8*>(A + (size_t)(m0 + r * 16 + lr) * NF + k0);
        #pragma unroll
        for (int c = 0; c < 4; ++c)
            b[c] = *reinterpret_cast<const bf16x8*>(WT + (size_t)(n0 + c * 16 + lr) * NF + k0);
        #pragma unroll
        for (int r = 0; r < 4; ++r)
            #pragma unroll
            for (int c = 0; c < 4; ++c)
                acc[r][c] = __builtin_amdgcn_mfma_f32_16x16x32_bf16(a[r], b[c], acc[r][c], 0, 0, 0);
    }
    #pragma unroll
    for (int r = 0; r < 4; ++r) {
        #pragma unroll
        for (int reg = 0; reg < 4; ++reg) {
            int m = m0 + r * 16 + lg * 4 + reg;
            #pragma unroll
            for (int c = 0; c < 4; ++c) {
                int col = n0 + c * 16 + lr;
                float v = acc[r][c][reg];
                if (addb) v += b1[col];
                OUT[(size_t)m * NF + col] = f2b(v);
            }
        }
    }
}

// ---------- aggregation (chunked): out = (relu?)(HS + sum_e w_e * SUP[col_e] + bias) ----------
// chunk = blockIdx % 8 -> pins each 3.2MB SUP chunk to one XCD's L2 (round-robin dispatch).
// 8-lane subgroup per node per chunk; lane covers 2 features (1 u32).
__global__ void k_aggregate_c(const u32* __restrict__ SUPc, const float2* __restrict__ HS2,
                              const int* __restrict__ rowptr, const int* __restrict__ ccol,
                              const float* __restrict__ cw, const float2* __restrict__ bias2,
                              u32* __restrict__ Hout, float2* __restrict__ Zout, int relu) {
    int chunk = blockIdx.x & 7;
    int nb = blockIdx.x >> 3;
    int l = threadIdx.x & 63, w = threadIdx.x >> 6;
    int sub = l >> 3, sl = l & 7;
    int node = nb * 32 + w * 8 + sub;
    if (node >= N_NODES) return;
    const u32* base = SUPc + (size_t)chunk * MPAD * 8;
    int e0 = rowptr[node], e1 = rowptr[node + 1];
    float a0 = 0.f, a1 = 0.f;
    int e = e0;
    for (; e + 4 <= e1; e += 4) {
        int c0 = ccol[e], c1 = ccol[e + 1], c2 = ccol[e + 2], c3 = ccol[e + 3];
        float w0 = cw[e], w1 = cw[e + 1], w2 = cw[e + 2], w3 = cw[e + 3];
        u32 v0 = base[(size_t)c0 * 8 + sl];
        u32 v1 = base[(size_t)c1 * 8 + sl];
        u32 v2 = base[(size_t)c2 * 8 + sl];
        u32 v3 = base[(size_t)c3 * 8 + sl];
        a0 = fmaf(w0, b2f((u16)(v0 & 0xffff)), a0); a1 = fmaf(w0, b2f((u16)(v0 >> 16)), a1);
        a0 = fmaf(w1, b2f((u16)(v1 & 0xffff)), a0); a1 = fmaf(w1, b2f((u16)(v1 >> 16)), a1);
        a0 = fmaf(w2, b2f((u16)(v2 & 0xffff)), a0); a1 = fmaf(w2, b2f((u16)(v2 >> 16)), a1);
        a0 = fmaf(w3, b2f((u16)(v3 & 0xffff)), a0); a1 = fmaf(w3, b2f((u16)(v3 >> 16)), a1);
    }
    for (; e < e1; ++e) {
        int c = ccol[e];
        float wgt = cw[e];
        u32 v = base[(size_t)c * 8 + sl];
        a0 = fmaf(wgt, b2f((u16)(v & 0xffff)), a0);
        a1 = fmaf(wgt, b2f((u16)(v >> 16)), a1);
    }
    size_t oidx = (size_t)node * 64 + chunk * 8 + sl;
    float2 hsv = HS2[oidx];
    float2 bv  = bias2[chunk * 8 + sl];
    float o0 = hsv.x + a0 + bv.x;
    float o1 = hsv.y + a1 + bv.y;
    if (relu) { o0 = fmaxf(o0, 0.f); o1 = fmaxf(o1, 0.f); }
    Hout[oidx] = (u32)f2b(o0) | ((u32)f2b(o1) << 16);
    if (Zout) Zout[oidx] = make_float2(o0, o1);
}

// ---------- pair decoder: p = sigmoid( sum_f relu(U[xi][f]+V[yi][f]) * w2[f] + b2 ) ----------
// 4 lanes per pair; lane j covers features [j*32, j*32+32)
__global__ void k_pairdec(const u16* __restrict__ U, const u16* __restrict__ V,
                          const int* __restrict__ xidx, const int* __restrict__ yidx,
                          const float* __restrict__ w2, const float* __restrict__ b2,
                          float* __restrict__ outp) {
    int t = blockIdx.x * 256 + threadIdx.x;
    int pair = t >> 2;
    int j = t & 3;
    if (pair >= N_PAIRS) return;
    int xi = xidx[pair], yi = yidx[pair];
    const bf16x8* up = reinterpret_cast<const bf16x8*>(U + (size_t)xi * NF + j * 32);
    const bf16x8* vp = reinterpret_cast<const bf16x8*>(V + (size_t)yi * NF + j * 32);
    bf16x8 uu[4], vv[4];
    #pragma unroll
    for (int it = 0; it < 4; ++it) { uu[it] = up[it]; vv[it] = vp[it]; }
    const float4* w4 = reinterpret_cast<const float4*>(w2 + j * 32);
    float acc = 0.f;
    #pragma unroll
    for (int it = 0; it < 4; ++it) {
        float4 wa = w4[it * 2], wb = w4[it * 2 + 1];
        float h;
        h = fmaxf((float)uu[it][0] + (float)vv[it][0], 0.f); acc = fmaf(h, wa.x, acc);
        h = fmaxf((float)uu[it][1] + (float)vv[it][1], 0.f); acc = fmaf(h, wa.y, acc);
        h = fmaxf((float)uu[it][2] + (float)vv[it][2], 0.f); acc = fmaf(h, wa.z, acc);
        h = fmaxf((float)uu[it][3] + (float)vv[it][3], 0.f); acc = fmaf(h, wa.w, acc);
        h = fmaxf((float)uu[it][4] + (float)vv[it][4], 0.f); acc = fmaf(h, wb.x, acc);
        h = fmaxf((float)uu[it][5] + (float)vv[it][5], 0.f); acc = fmaf(h, wb.y, acc);
        h = fmaxf((float)uu[it][6] + (float)vv[it][6], 0.f); acc = fmaf(h, wb.z, acc);
        h = fmaxf((float)uu[it][7] + (float)vv[it][7], 0.f); acc = fmaf(h, wb.w, acc);
    }
    acc += __shfl_xor(acc, 1, 64);
    acc += __shfl_xor(acc, 2, 64);
    if (j == 0) outp[pair] = 1.f / (1.f + __expf(-(acc + b2[0])));
}

extern "C" void kernel_launch(void* const* d_in, const int* in_sizes, int n_in,
                              void* d_out, int out_size, void* d_ws, size_t ws_size,
                              hipStream_t stream) {
    const float* x      = (const float*)d_in[0];
    const int* edge_row = (const int*)d_in[1];
    const int* edge_col = (const int*)d_in[2];
    const float* edge_w = (const float*)d_in[3];
    const int* x_idx    = (const int*)d_in[4];
    const int* y_idx    = (const int*)d_in[5];
    const float* gws[3] = {(const float*)d_in[6], (const float*)d_in[9],  (const float*)d_in[12]};
    const float* gwn[3] = {(const float*)d_in[7], (const float*)d_in[10], (const float*)d_in[13]};
    const float* gb[3]  = {(const float*)d_in[8], (const float*)d_in[11], (const float*)d_in[14]};
    const float* dw1 = (const float*)d_in[15];
    const float* db1 = (const float*)d_in[16];
    const float* dw2 = (const float*)d_in[17];
    const float* db2 = (const float*)d_in[18];
    float* out_p = (float*)d_out;        // [N_PAIRS]
    float* out_z = out_p + N_PAIRS;      // [N_NODES*128]

    char* base = (char*)d_ws;
    size_t off = 0;
    auto alloc = [&](size_t bytes) -> void* {
        void* p = base + off;
        off = (off + bytes + 255) & ~(size_t)255;
        return p;
    };
    u16* h0   = (u16*)alloc((size_t)MPAD * NF * 2);
    u16* h1   = (u16*)alloc((size_t)MPAD * NF * 2);
    u16* supc = (u16*)alloc((size_t)MPAD * NF * 2);
    float* hs = (float*)alloc((size_t)MPAD * NF * 4);
    u16* wT[6];
    for (int i = 0; i < 6; ++i) wT[i] = (u16*)alloc(128 * 128 * 2);
    u16* w1aT = (u16*)alloc(128 * 128 * 2);
    u16* w1bT = (u16*)alloc(128 * 128 * 2);
    int* deg    = (int*)alloc(N_NODES * 4);
    int* incl   = (int*)alloc(N_NODES * 4);
    int* bsums  = (int*)alloc(128 * 4);
    int* rowptr = (int*)alloc((N_NODES + 1) * 4);
    int* cursor = (int*)alloc(N_NODES * 4);
    int* ccol   = (int*)alloc(N_EDGES * 4);
    float* cwt  = (float*)alloc(N_EDGES * 4);
    // U,V alias the hs buffer (free after the last aggregate reads it)
    u16* U = (u16*)hs;
    u16* V = U + (size_t)MPAD * NF;

    hipMemsetAsync(deg, 0, N_NODES * 4, stream);

    // weight conversion (transposed to [N][K] bf16)
    for (int l = 0; l < 3; ++l) {
        k_convT<<<64, 256, 0, stream>>>(gws[l], wT[2 * l],     128, 128);
        k_convT<<<64, 256, 0, stream>>>(gwn[l], wT[2 * l + 1], 128, 128);
    }
    k_convT<<<64, 256, 0, stream>>>(dw1,             w1aT, 128, 128);
    k_convT<<<64, 256, 0, stream>>>(dw1 + 128 * 128, w1bT, 128, 128);
    k_convX<<<(MPAD * 64 + 255) / 256, 256, 0, stream>>>((const float2*)x, (u32*)h0);

    // CSR build
    k_hist<<<(N_EDGES + 255) / 256, 256, 0, stream>>>(edge_row, deg);
    k_scan1<<<98, 1024, 0, stream>>>(deg, incl, bsums);
    k_scan2<<<1, 128, 0, stream>>>(bsums, 98);
    k_scan3<<<(N_NODES + 255) / 256, 256, 0, stream>>>(incl, bsums, rowptr, cursor);
    k_scatter<<<(N_EDGES + 255) / 256, 256, 0, stream>>>(edge_row, edge_col, edge_w, cursor, ccol, cwt);

    const int GB = MPAD / 64;             // 1563
    const int AB = 8 * ((N_NODES + 31) / 32);  // 8 chunks * 3125 nodeblocks

    // layer 1: x -> h1
    k_gemm_pair<<<GB, 256, 0, stream>>>(h0, wT[0], wT[1], hs, supc);
    k_aggregate_c<<<AB, 256, 0, stream>>>((const u32*)supc, (const float2*)hs, rowptr, ccol, cwt,
                                          (const float2*)gb[0], (u32*)h1, nullptr, 1);
    // layer 2: h1 -> h0
    k_gemm_pair<<<GB, 256, 0, stream>>>(h1, wT[2], wT[3], hs, supc);
    k_aggregate_c<<<AB, 256, 0, stream>>>((const u32*)supc, (const float2*)hs, rowptr, ccol, cwt,
                                          (const float2*)gb[1], (u32*)h0, nullptr, 1);
    // layer 3: h0 -> h1 (=z bf16) + z f32 to d_out
    k_gemm_pair<<<GB, 256, 0, stream>>>(h0, wT[4], wT[5], hs, supc);
    k_aggregate_c<<<AB, 256, 0, stream>>>((const u32*)supc, (const float2*)hs, rowptr, ccol, cwt,
                                          (const float2*)gb[2], (u32*)h1, (float2*)out_z, 0);
    // decoder precompute: U = z@W1a + b1, V = z@W1b  (into the freed hs region)
    k_gemm_uv<<<GB, 256, 0, stream>>>(h1, w1aT, w1bT, db1, U, V);
    // pair decoder
    k_pairdec<<<(N_PAIRS * 4 + 255) / 256, 256, 0, stream>>>(U, V, x_idx, y_idx, dw2, db2, out_p);
}